// Round 3
// baseline (362.576 us; speedup 1.0000x reference)
//
#include <hip/hip_runtime.h>
#include <cstdint>
#include <cstddef>

// Dual attention (channel attention), B=16 S=512 D=1024 H=16 dk=64.
// Round 3: scores/mix were latency-bound (Occ 17%, VALU 4%, HBM 6%) -> more
// blocks; 3 projection GEMMs merged into one grid.z=3 launch (2 blocks/CU ->
// 6 blocks/CU); scores-memset folded into pack tail blocks.
// Pipeline:
//   1. pack: f32 -> fp16 (q,k,v,Wq,Wk,Wv,Wo) + zero scores
//   2. Pq,Pk,Pv = fp16 MFMA GEMM (A @ W^T + b), f32 outputs (one launch, z=3)
//   3. scores[b,i,j] = 0.25 * sum_{s,c} Pq[b,s,64i+c]*Pk[b,s,64j+c]
//   4. softmax -> attn (d_out tail); Mm = I + beta*attn
//   5. xmix[r,64i+c] = f16( sum_j Mm[i,j]*Pv[r,64j+c] )
//   6. out = f16 GEMM(xmix, Wo^T) + bo -> d_out
// mask (d_in[3]) and adj (d_in[4]) are unused by the reference.

#define DIM 1024

typedef _Float16 f16_t;
typedef _Float16 f16x4_t __attribute__((ext_vector_type(4)));
typedef _Float16 f16x8_t __attribute__((ext_vector_type(8)));
typedef float    f32x4_t __attribute__((ext_vector_type(4)));

__device__ __forceinline__ void async_ld16(const void* g, void* l) {
    __builtin_amdgcn_global_load_lds((const __attribute__((address_space(1))) void*)g,
                                     (__attribute__((address_space(3))) void*)l,
                                     16, 0, 0);
}

// ---------------------------------------------------------------- pack kernel
// float4 units: q 2097152 | k 2097152 | v 2097152 | Wq 262144 | Wk 262144
//               | Wv 262144 | Wo 262144 => 7340032 units. Tail 16 blocks zero
//               the 4096-float scores buffer. Grid 28688 blocks.
__global__ __launch_bounds__(256) void pack_kernel(
    const float* __restrict__ q, const float* __restrict__ k, const float* __restrict__ v,
    const float* __restrict__ Wq, const float* __restrict__ Wk,
    const float* __restrict__ Wv, const float* __restrict__ Wo,
    f16_t* __restrict__ Aq, f16_t* __restrict__ Ak, f16_t* __restrict__ Av,
    f16_t* __restrict__ Bq, f16_t* __restrict__ Bk,
    f16_t* __restrict__ Bv, f16_t* __restrict__ Bo,
    float* __restrict__ scores)
{
    const int u = blockIdx.x * 256 + threadIdx.x;
    if (u >= 7340032) {            // tail: zero scores accumulator
        scores[u - 7340032] = 0.f;
        return;
    }
    const float* src; f16_t* dst; int i;
    if (u < 2097152)      { src = q;  dst = Aq; i = u; }
    else if (u < 4194304) { src = k;  dst = Ak; i = u - 2097152; }
    else if (u < 6291456) { src = v;  dst = Av; i = u - 4194304; }
    else if (u < 6553600) { src = Wq; dst = Bq; i = u - 6291456; }
    else if (u < 6815744) { src = Wk; dst = Bk; i = u - 6553600; }
    else if (u < 7077888) { src = Wv; dst = Bv; i = u - 6815744; }
    else                  { src = Wo; dst = Bo; i = u - 7077888; }
    float4 s = ((const float4*)src)[i];
    f16x4_t h;
    h[0] = (f16_t)s.x; h[1] = (f16_t)s.y; h[2] = (f16_t)s.z; h[3] = (f16_t)s.w;
    ((f16x4_t*)dst)[i] = h;
}

// ---------------------------------------------------------------- GEMM body
// C[m,n] = sum_k A[m,k]*B[n,k] + bias[n]. A [8192,1024] f16 row-major,
// B [1024,1024] f16 row-major (W [out,in] -> C = A@W^T). Tile 128x128, BK=64,
// 4 waves. LDS XOR-swizzled in 16B column units: LDS(row, cu) =
// global(row, cu ^ (row&7)) so 16-lane ds_read_b128 fragment reads spread
// across all banks (2-way aliasing only, free per m136).
__device__ __forceinline__ void gemm_body(
    const f16_t* __restrict__ A, const f16_t* __restrict__ B,
    const float* __restrict__ bias, float* __restrict__ C,
    f16_t* As, f16_t* Bs, int tileM, int tileN)
{
    const int tid  = threadIdx.x;
    const int lane = tid & 63;
    const int w    = tid >> 6;
    const int wm = (w & 1) << 6;
    const int wn = (w >> 1) << 6;

    f32x4_t acc[4][4];
#pragma unroll
    for (int i = 0; i < 4; ++i)
#pragma unroll
        for (int j = 0; j < 4; ++j)
            acc[i][j] = (f32x4_t){0.f, 0.f, 0.f, 0.f};

    const int srow = lane >> 3;                       // staging row in 8-row chunk
    const int scol = ((lane & 7) ^ (lane >> 3)) << 3; // swizzled fetch col (elems)
    const int arow = lane & 15;                       // mfma frag row/col
    const int sx   = lane & 7;                        // reader swizzle (= row&7)
    const int kqu  = lane >> 4;                       // frag k 16B-unit (0..3)

    for (int kt = 0; kt < 16; ++kt) {
        const int k0 = kt << 6;
#pragma unroll
        for (int t = 0; t < 4; ++t) {
            const int row = (w << 5) + (t << 3);      // wave-uniform chunk base
            async_ld16(A + (size_t)(tileM + row + srow) * DIM + k0 + scol,
                       (void*)(As + row * 64));
            async_ld16(B + (size_t)(tileN + row + srow) * DIM + k0 + scol,
                       (void*)(Bs + row * 64));
        }
        __syncthreads();
#pragma unroll
        for (int kk = 0; kk < 2; ++kk) {              // two 16B-unit groups
            const int cu = ((kk << 2) + kqu) ^ sx;    // swizzled LDS column unit
            f16x8_t af[4], bfv[4];
#pragma unroll
            for (int mt = 0; mt < 4; ++mt)
                af[mt] = *(const f16x8_t*)(As + (wm + (mt << 4) + arow) * 64 + (cu << 3));
#pragma unroll
            for (int nt = 0; nt < 4; ++nt)
                bfv[nt] = *(const f16x8_t*)(Bs + (wn + (nt << 4) + arow) * 64 + (cu << 3));
#pragma unroll
            for (int mt = 0; mt < 4; ++mt)
#pragma unroll
                for (int nt = 0; nt < 4; ++nt)
                    acc[mt][nt] = __builtin_amdgcn_mfma_f32_16x16x32_f16(
                        af[mt], bfv[nt], acc[mt][nt], 0, 0, 0);
        }
        __syncthreads();
    }

    // C/D layout: col = lane&15, row = (lane>>4)*4 + reg
    const int rq = (lane >> 4) << 2;
#pragma unroll
    for (int nt = 0; nt < 4; ++nt) {
        const int col = tileN + wn + (nt << 4) + arow;
        const float bv = bias[col];
#pragma unroll
        for (int mt = 0; mt < 4; ++mt) {
            const int row = tileM + wm + (mt << 4) + rq;
#pragma unroll
            for (int r = 0; r < 4; ++r)
                C[(size_t)(row + r) * DIM + col] = acc[mt][nt][r] + bv;
        }
    }
}

struct Gemm3Args {
    const f16_t* A[3];
    const f16_t* B[3];
    const float* bias[3];
    float*       C[3];
};

// three projection GEMMs in one launch: grid (64, 8, 3)
__global__ __launch_bounds__(256) void gemm3(Gemm3Args args)
{
    __shared__ __align__(16) f16_t As[128 * 64];
    __shared__ __align__(16) f16_t Bs[128 * 64];
    const int z = blockIdx.z;
    gemm_body(args.A[z], args.B[z], args.bias[z], args.C[z],
              As, Bs, blockIdx.x * 128, blockIdx.y * 128);
}

// single GEMM (output projection)
__global__ __launch_bounds__(256) void gemm_f16(
    const f16_t* __restrict__ A, const f16_t* __restrict__ B,
    const float* __restrict__ bias, float* __restrict__ C)
{
    __shared__ __align__(16) f16_t As[128 * 64];
    __shared__ __align__(16) f16_t Bs[128 * 64];
    gemm_body(A, B, bias, C, As, Bs, blockIdx.x * 128, blockIdx.y * 128);
}

// ---------------------------------------------------------------- scores
// grid (16 batches, 64 chunks of 8 rows). lane = c (0..63), wave w owns 4 j's.
__global__ __launch_bounds__(256) void scores_kernel(
    const float* __restrict__ Pq, const float* __restrict__ Pk,
    float* __restrict__ scores)
{
    const int b = blockIdx.x;
    const int chunk = blockIdx.y;
    const int lane = threadIdx.x & 63;
    const int w = threadIdx.x >> 6;

    float acc[16][4];
#pragma unroll
    for (int i = 0; i < 16; ++i)
#pragma unroll
        for (int jj = 0; jj < 4; ++jj) acc[i][jj] = 0.f;

    const int r0 = b * 512 + chunk * 8;
#pragma unroll 4
    for (int rr = 0; rr < 8; ++rr) {
        const float* qrow = Pq + (size_t)(r0 + rr) * DIM;
        const float* krow = Pk + (size_t)(r0 + rr) * DIM;
        float kv[4];
#pragma unroll
        for (int jj = 0; jj < 4; ++jj)
            kv[jj] = krow[(w * 4 + jj) * 64 + lane];
#pragma unroll
        for (int i = 0; i < 16; ++i) {
            float qv = qrow[i * 64 + lane];
#pragma unroll
            for (int jj = 0; jj < 4; ++jj) acc[i][jj] += qv * kv[jj];
        }
    }
#pragma unroll
    for (int i = 0; i < 16; ++i)
#pragma unroll
        for (int jj = 0; jj < 4; ++jj) {
            float v2 = acc[i][jj];
            for (int off = 32; off; off >>= 1) v2 += __shfl_down(v2, off);
            if (lane == 0)
                atomicAdd(&scores[b * 256 + i * 16 + w * 4 + jj], v2);
        }
}

// ---------------------------------------------------------------- softmax
// 1 block, 256 threads: thread t = (b,i) row; attn -> d_out tail; Mm = I + beta*attn
__global__ __launch_bounds__(256) void softmax_kernel(
    const float* __restrict__ scores, const float* __restrict__ beta_p,
    float* __restrict__ attn_out, float* __restrict__ Mm)
{
    const int t = threadIdx.x;
    const int i = t & 15;
    const float beta = beta_p[0];
    float s[16];
    float mx = -1e30f;
#pragma unroll
    for (int j = 0; j < 16; ++j) {
        s[j] = scores[t * 16 + j] * 0.25f;   // 1/sqrt(h), h=16
        mx = fmaxf(mx, s[j]);
    }
    float sum = 0.f;
#pragma unroll
    for (int j = 0; j < 16; ++j) { s[j] = expf(s[j] - mx); sum += s[j]; }
    const float inv = 1.f / sum;
#pragma unroll
    for (int j = 0; j < 16; ++j) {
        float a = s[j] * inv;
        attn_out[t * 16 + j] = a;
        Mm[t * 16 + j] = beta * a + ((j == i) ? 1.f : 0.f);
    }
}

// ---------------------------------------------------------------- channel mix
// xmix[r,64i+c] = f16( sum_j Mm[b,i,j] * Pv[r,64j+c] ). 1024 blocks x 8 rows.
__global__ __launch_bounds__(256) void mix_kernel(
    const float* __restrict__ Pv, const float* __restrict__ Mm,
    f16_t* __restrict__ xmix)
{
    __shared__ float Msh[256];
    const int rbase = blockIdx.x * 8;
    const int b = rbase >> 9;
    Msh[threadIdx.x] = Mm[b * 256 + threadIdx.x];
    __syncthreads();
    const int w = threadIdx.x >> 6;
    const int lane = threadIdx.x & 63;
#pragma unroll
    for (int rr = 0; rr < 2; ++rr) {
        const int r = rbase + w * 2 + rr;
        const float* vrow = Pv + (size_t)r * DIM;
        float v[16];
#pragma unroll
        for (int j = 0; j < 16; ++j) v[j] = vrow[j * 64 + lane];
#pragma unroll
        for (int i = 0; i < 16; ++i) {
            float x = 0.f;
#pragma unroll
            for (int j = 0; j < 16; ++j) x += Msh[i * 16 + j] * v[j];
            xmix[(size_t)r * DIM + i * 64 + lane] = (f16_t)x;
        }
    }
}

// ---------------------------------------------------------------- launch
extern "C" void kernel_launch(void* const* d_in, const int* in_sizes, int n_in,
                              void* d_out, int out_size, void* d_ws, size_t ws_size,
                              hipStream_t stream)
{
    (void)in_sizes; (void)n_in; (void)out_size; (void)ws_size;
    const float* q    = (const float*)d_in[0];
    const float* k    = (const float*)d_in[1];
    const float* v    = (const float*)d_in[2];
    // d_in[3] mask, d_in[4] adj: unused by reference
    const float* Wq   = (const float*)d_in[5];
    const float* bq   = (const float*)d_in[6];
    const float* Wk   = (const float*)d_in[7];
    const float* bk   = (const float*)d_in[8];
    const float* Wv   = (const float*)d_in[9];
    const float* bv   = (const float*)d_in[10];
    const float* Wo   = (const float*)d_in[11];
    const float* bo   = (const float*)d_in[12];
    const float* beta = (const float*)d_in[13];

    float* out  = (float*)d_out;                     // [8192,1024]
    float* attn = (float*)d_out + 8388608;           // [16,16,16]

    char* p = (char*)d_ws;
    auto take = [&](size_t n) -> char* {
        char* cur = p; p += (n + 255) & ~(size_t)255; return cur;
    };
    f16_t* Aq = (f16_t*)take(16777216);
    f16_t* Ak = (f16_t*)take(16777216);
    f16_t* Av = (f16_t*)take(16777216);
    f16_t* Bq = (f16_t*)take(2097152);
    f16_t* Bk = (f16_t*)take(2097152);
    f16_t* Bv = (f16_t*)take(2097152);
    f16_t* Bo = (f16_t*)take(2097152);
    float* Pq = (float*)take(33554432);
    float* Pk = (float*)take(33554432);
    float* Pv = (float*)take(33554432);
    float* scores = (float*)take(16384);
    float* Mm     = (float*)take(16384);
    f16_t* xmix = Aq;  // Aq dead after Pq GEMM; reuse for xmix

    pack_kernel<<<28688, 256, 0, stream>>>(q, k, v, Wq, Wk, Wv, Wo,
                                           Aq, Ak, Av, Bq, Bk, Bv, Bo, scores);

    Gemm3Args ga;
    ga.A[0] = Aq; ga.A[1] = Ak; ga.A[2] = Av;
    ga.B[0] = Bq; ga.B[1] = Bk; ga.B[2] = Bv;
    ga.bias[0] = bq; ga.bias[1] = bk; ga.bias[2] = bv;
    ga.C[0] = Pq; ga.C[1] = Pk; ga.C[2] = Pv;
    gemm3<<<dim3(64, 8, 3), 256, 0, stream>>>(ga);

    scores_kernel<<<dim3(16, 64), 256, 0, stream>>>(Pq, Pk, scores);
    softmax_kernel<<<1, 256, 0, stream>>>(scores, beta, attn, Mm);
    mix_kernel<<<1024, 256, 0, stream>>>(Pv, Mm, xmix);
    gemm_f16<<<dim3(64, 8), 256, 0, stream>>>(xmix, Bo, bo, out);
}

// Round 4
// 291.356 us; speedup vs baseline: 1.2444x; 1.2444x over previous
//
#include <hip/hip_runtime.h>
#include <cstdint>
#include <cstddef>

// Dual attention (channel attention), B=16 S=512 D=1024 H=16 dk=64.
// Round 4: scores_kernel was half scalar-load latency / half shuffle+atomic
// epilogue (R3 post-mortem: +512 blocks => +45us). Replaced with MFMA:
// scores[b] = Qf Kf^T is a 16x16x32768 f16 GEMM per batch. Pq/Pk are now
// written as f16 by gemm3 (their only consumer is scores) -> 32MB read,
// one mfma per 32-k-chunk, LDS 4-wave reduce, 256 atomics/block.
// Pipeline:
//   1. pack: f32 -> fp16 (q,k,v,Wq,Wk,Wv,Wo) + zero scores
//   2. gemm3 (z=3): Pq16,Pk16 = f16(A@W^T+b) [f16 out]; Pv = f32 out
//   3. scores[b,i,j] = sum_{s,c} Pq16[b,s,64i+c]*Pk16[b,s,64j+c]  (MFMA)
//   4. softmax (x0.25 scale) -> attn (d_out tail); Mm = I + beta*attn
//   5. xmix[r,64i+c] = f16( sum_j Mm[i,j]*Pv[r,64j+c] )
//   6. out = f16 GEMM(xmix, Wo^T) + bo -> d_out
// mask (d_in[3]) and adj (d_in[4]) are unused by the reference.

#define DIM 1024

typedef _Float16 f16_t;
typedef _Float16 f16x4_t __attribute__((ext_vector_type(4)));
typedef _Float16 f16x8_t __attribute__((ext_vector_type(8)));
typedef float    f32x4_t __attribute__((ext_vector_type(4)));

__device__ __forceinline__ void async_ld16(const void* g, void* l) {
    __builtin_amdgcn_global_load_lds((const __attribute__((address_space(1))) void*)g,
                                     (__attribute__((address_space(3))) void*)l,
                                     16, 0, 0);
}

// ---------------------------------------------------------------- pack kernel
// float4 units: q 2097152 | k 2097152 | v 2097152 | Wq 262144 | Wk 262144
//               | Wv 262144 | Wo 262144 => 7340032 units. Tail 16 blocks zero
//               the 4096-float scores buffer. Grid 28688 blocks.
__global__ __launch_bounds__(256) void pack_kernel(
    const float* __restrict__ q, const float* __restrict__ k, const float* __restrict__ v,
    const float* __restrict__ Wq, const float* __restrict__ Wk,
    const float* __restrict__ Wv, const float* __restrict__ Wo,
    f16_t* __restrict__ Aq, f16_t* __restrict__ Ak, f16_t* __restrict__ Av,
    f16_t* __restrict__ Bq, f16_t* __restrict__ Bk,
    f16_t* __restrict__ Bv, f16_t* __restrict__ Bo,
    float* __restrict__ scores)
{
    const int u = blockIdx.x * 256 + threadIdx.x;
    if (u >= 7340032) {            // tail: zero scores accumulator
        scores[u - 7340032] = 0.f;
        return;
    }
    const float* src; f16_t* dst; int i;
    if (u < 2097152)      { src = q;  dst = Aq; i = u; }
    else if (u < 4194304) { src = k;  dst = Ak; i = u - 2097152; }
    else if (u < 6291456) { src = v;  dst = Av; i = u - 4194304; }
    else if (u < 6553600) { src = Wq; dst = Bq; i = u - 6291456; }
    else if (u < 6815744) { src = Wk; dst = Bk; i = u - 6553600; }
    else if (u < 7077888) { src = Wv; dst = Bv; i = u - 6815744; }
    else                  { src = Wo; dst = Bo; i = u - 7077888; }
    float4 s = ((const float4*)src)[i];
    f16x4_t h;
    h[0] = (f16_t)s.x; h[1] = (f16_t)s.y; h[2] = (f16_t)s.z; h[3] = (f16_t)s.w;
    ((f16x4_t*)dst)[i] = h;
}

// ---------------------------------------------------------------- GEMM body
// C[m,n] = sum_k A[m,k]*B[n,k] + bias[n]. A [8192,1024] f16 row-major,
// B [1024,1024] f16 row-major (W [out,in] -> C = A@W^T). Tile 128x128, BK=64,
// 4 waves. LDS XOR-swizzled in 16B column units: LDS(row, cu) =
// global(row, cu ^ (row&7)) so 16-lane ds_read_b128 fragment reads spread
// across all banks (2-way aliasing only, free per m136).
// Output: f16 to C16 if C16 != null, else f32 to C.
__device__ __forceinline__ void gemm_body(
    const f16_t* __restrict__ A, const f16_t* __restrict__ B,
    const float* __restrict__ bias, float* __restrict__ C, f16_t* __restrict__ C16,
    f16_t* As, f16_t* Bs, int tileM, int tileN)
{
    const int tid  = threadIdx.x;
    const int lane = tid & 63;
    const int w    = tid >> 6;
    const int wm = (w & 1) << 6;
    const int wn = (w >> 1) << 6;

    f32x4_t acc[4][4];
#pragma unroll
    for (int i = 0; i < 4; ++i)
#pragma unroll
        for (int j = 0; j < 4; ++j)
            acc[i][j] = (f32x4_t){0.f, 0.f, 0.f, 0.f};

    const int srow = lane >> 3;                       // staging row in 8-row chunk
    const int scol = ((lane & 7) ^ (lane >> 3)) << 3; // swizzled fetch col (elems)
    const int arow = lane & 15;                       // mfma frag row/col
    const int sx   = lane & 7;                        // reader swizzle (= row&7)
    const int kqu  = lane >> 4;                       // frag k 16B-unit (0..3)

    for (int kt = 0; kt < 16; ++kt) {
        const int k0 = kt << 6;
#pragma unroll
        for (int t = 0; t < 4; ++t) {
            const int row = (w << 5) + (t << 3);      // wave-uniform chunk base
            async_ld16(A + (size_t)(tileM + row + srow) * DIM + k0 + scol,
                       (void*)(As + row * 64));
            async_ld16(B + (size_t)(tileN + row + srow) * DIM + k0 + scol,
                       (void*)(Bs + row * 64));
        }
        __syncthreads();
#pragma unroll
        for (int kk = 0; kk < 2; ++kk) {              // two 16B-unit groups
            const int cu = ((kk << 2) + kqu) ^ sx;    // swizzled LDS column unit
            f16x8_t af[4], bfv[4];
#pragma unroll
            for (int mt = 0; mt < 4; ++mt)
                af[mt] = *(const f16x8_t*)(As + (wm + (mt << 4) + arow) * 64 + (cu << 3));
#pragma unroll
            for (int nt = 0; nt < 4; ++nt)
                bfv[nt] = *(const f16x8_t*)(Bs + (wn + (nt << 4) + arow) * 64 + (cu << 3));
#pragma unroll
            for (int mt = 0; mt < 4; ++mt)
#pragma unroll
                for (int nt = 0; nt < 4; ++nt)
                    acc[mt][nt] = __builtin_amdgcn_mfma_f32_16x16x32_f16(
                        af[mt], bfv[nt], acc[mt][nt], 0, 0, 0);
        }
        __syncthreads();
    }

    // C/D layout: col = lane&15, row = (lane>>4)*4 + reg
    const int rq = (lane >> 4) << 2;
    if (C16) {
#pragma unroll
        for (int nt = 0; nt < 4; ++nt) {
            const int col = tileN + wn + (nt << 4) + arow;
            const float bv = bias[col];
#pragma unroll
            for (int mt = 0; mt < 4; ++mt) {
                const int row = tileM + wm + (mt << 4) + rq;
#pragma unroll
                for (int r = 0; r < 4; ++r)
                    C16[(size_t)(row + r) * DIM + col] = (f16_t)(acc[mt][nt][r] + bv);
            }
        }
    } else {
#pragma unroll
        for (int nt = 0; nt < 4; ++nt) {
            const int col = tileN + wn + (nt << 4) + arow;
            const float bv = bias[col];
#pragma unroll
            for (int mt = 0; mt < 4; ++mt) {
                const int row = tileM + wm + (mt << 4) + rq;
#pragma unroll
                for (int r = 0; r < 4; ++r)
                    C[(size_t)(row + r) * DIM + col] = acc[mt][nt][r] + bv;
            }
        }
    }
}

struct Gemm3Args {
    const f16_t* A[3];
    const f16_t* B[3];
    const float* bias[3];
    float*       C[3];    // z=2 (Pv) f32 out
    f16_t*       C16[3];  // z=0,1 (Pq16, Pk16) f16 out
};

// three projection GEMMs in one launch: grid (64, 8, 3)
__global__ __launch_bounds__(256) void gemm3(Gemm3Args args)
{
    __shared__ __align__(16) f16_t As[128 * 64];
    __shared__ __align__(16) f16_t Bs[128 * 64];
    const int z = blockIdx.z;
    gemm_body(args.A[z], args.B[z], args.bias[z], args.C[z], args.C16[z],
              As, Bs, blockIdx.x * 128, blockIdx.y * 128);
}

// single GEMM, f32 out (output projection)
__global__ __launch_bounds__(256) void gemm_f16(
    const f16_t* __restrict__ A, const f16_t* __restrict__ B,
    const float* __restrict__ bias, float* __restrict__ C)
{
    __shared__ __align__(16) f16_t As[128 * 64];
    __shared__ __align__(16) f16_t Bs[128 * 64];
    gemm_body(A, B, bias, C, nullptr, As, Bs, blockIdx.x * 128, blockIdx.y * 128);
}

// ---------------------------------------------------------------- scores
// scores[b,i,j] = sum_n Qf[b,i,n] Kf[b,j,n], n = s*64+c. MFMA 16x16x32 per
// 32-c chunk. Grid (16 batches, 32 slices); wave w owns s = slice*16+w*4..+3.
// A-frag: lane reads Qf[i=lane&15][k-chunk], 16B contiguous; same for B/Kf.
// Block epilogue: LDS reduce over 4 waves, then 256 atomics (32 contenders).
__global__ __launch_bounds__(256) void scores_kernel(
    const f16_t* __restrict__ Pq16, const f16_t* __restrict__ Pk16,
    float* __restrict__ scores)
{
    __shared__ float red[4][256];
    const int b = blockIdx.x;
    const int lane = threadIdx.x & 63;
    const int w = threadIdx.x >> 6;
    const int m  = lane & 15;              // i (A rows) / j (B rows)
    const int q8 = (lane >> 4) << 3;       // k-offset within 32-chunk

    f32x4_t acc = (f32x4_t){0.f, 0.f, 0.f, 0.f};
    const int s0 = blockIdx.y * 16 + w * 4;
#pragma unroll
    for (int ss = 0; ss < 4; ++ss) {
        const size_t rb = (size_t)(b * 512 + s0 + ss) * DIM;
        const f16_t* qrow = Pq16 + rb;
        const f16_t* krow = Pk16 + rb;
#pragma unroll
        for (int c0 = 0; c0 < 64; c0 += 32) {
            f16x8_t af = *(const f16x8_t*)(qrow + m * 64 + c0 + q8);
            f16x8_t bf = *(const f16x8_t*)(krow + m * 64 + c0 + q8);
            acc = __builtin_amdgcn_mfma_f32_16x16x32_f16(af, bf, acc, 0, 0, 0);
        }
    }
    // C/D: col(j) = lane&15, row(i) = (lane>>4)*4 + r
    const int rq = (lane >> 4) << 2;
#pragma unroll
    for (int r = 0; r < 4; ++r)
        red[w][(rq + r) * 16 + m] = acc[r];
    __syncthreads();
    const int t = threadIdx.x;
    const float sum = red[0][t] + red[1][t] + red[2][t] + red[3][t];
    atomicAdd(&scores[b * 256 + t], sum);
}

// ---------------------------------------------------------------- softmax
// 1 block, 256 threads: thread t = (b,i) row; attn -> d_out tail; Mm = I + beta*attn
__global__ __launch_bounds__(256) void softmax_kernel(
    const float* __restrict__ scores, const float* __restrict__ beta_p,
    float* __restrict__ attn_out, float* __restrict__ Mm)
{
    const int t = threadIdx.x;
    const int i = t & 15;
    const float beta = beta_p[0];
    float s[16];
    float mx = -1e30f;
#pragma unroll
    for (int j = 0; j < 16; ++j) {
        s[j] = scores[t * 16 + j] * 0.25f;   // 1/sqrt(h), h=16
        mx = fmaxf(mx, s[j]);
    }
    float sum = 0.f;
#pragma unroll
    for (int j = 0; j < 16; ++j) { s[j] = expf(s[j] - mx); sum += s[j]; }
    const float inv = 1.f / sum;
#pragma unroll
    for (int j = 0; j < 16; ++j) {
        float a = s[j] * inv;
        attn_out[t * 16 + j] = a;
        Mm[t * 16 + j] = beta * a + ((j == i) ? 1.f : 0.f);
    }
}

// ---------------------------------------------------------------- channel mix
// xmix[r,64i+c] = f16( sum_j Mm[b,i,j] * Pv[r,64j+c] ). 1024 blocks x 8 rows.
__global__ __launch_bounds__(256) void mix_kernel(
    const float* __restrict__ Pv, const float* __restrict__ Mm,
    f16_t* __restrict__ xmix)
{
    __shared__ float Msh[256];
    const int rbase = blockIdx.x * 8;
    const int b = rbase >> 9;
    Msh[threadIdx.x] = Mm[b * 256 + threadIdx.x];
    __syncthreads();
    const int w = threadIdx.x >> 6;
    const int lane = threadIdx.x & 63;
#pragma unroll
    for (int rr = 0; rr < 2; ++rr) {
        const int r = rbase + w * 2 + rr;
        const float* vrow = Pv + (size_t)r * DIM;
        float v[16];
#pragma unroll
        for (int j = 0; j < 16; ++j) v[j] = vrow[j * 64 + lane];
#pragma unroll
        for (int i = 0; i < 16; ++i) {
            float x = 0.f;
#pragma unroll
            for (int j = 0; j < 16; ++j) x += Msh[i * 16 + j] * v[j];
            xmix[(size_t)r * DIM + i * 64 + lane] = (f16_t)x;
        }
    }
}

// ---------------------------------------------------------------- launch
extern "C" void kernel_launch(void* const* d_in, const int* in_sizes, int n_in,
                              void* d_out, int out_size, void* d_ws, size_t ws_size,
                              hipStream_t stream)
{
    (void)in_sizes; (void)n_in; (void)out_size; (void)ws_size;
    const float* q    = (const float*)d_in[0];
    const float* k    = (const float*)d_in[1];
    const float* v    = (const float*)d_in[2];
    // d_in[3] mask, d_in[4] adj: unused by reference
    const float* Wq   = (const float*)d_in[5];
    const float* bq   = (const float*)d_in[6];
    const float* Wk   = (const float*)d_in[7];
    const float* bk   = (const float*)d_in[8];
    const float* Wv   = (const float*)d_in[9];
    const float* bv   = (const float*)d_in[10];
    const float* Wo   = (const float*)d_in[11];
    const float* bo   = (const float*)d_in[12];
    const float* beta = (const float*)d_in[13];

    float* out  = (float*)d_out;                     // [8192,1024]
    float* attn = (float*)d_out + 8388608;           // [16,16,16]

    char* p = (char*)d_ws;
    auto take = [&](size_t n) -> char* {
        char* cur = p; p += (n + 255) & ~(size_t)255; return cur;
    };
    f16_t* Aq = (f16_t*)take(16777216);
    f16_t* Ak = (f16_t*)take(16777216);
    f16_t* Av = (f16_t*)take(16777216);
    f16_t* Bq = (f16_t*)take(2097152);
    f16_t* Bk = (f16_t*)take(2097152);
    f16_t* Bv = (f16_t*)take(2097152);
    f16_t* Bo = (f16_t*)take(2097152);
    f16_t* Pq16 = (f16_t*)take(16777216);
    f16_t* Pk16 = (f16_t*)take(16777216);
    float* Pv = (float*)take(33554432);
    float* scores = (float*)take(16384);
    float* Mm     = (float*)take(16384);
    f16_t* xmix = Aq;  // Aq dead after gemm3; reuse for xmix

    pack_kernel<<<28688, 256, 0, stream>>>(q, k, v, Wq, Wk, Wv, Wo,
                                           Aq, Ak, Av, Bq, Bk, Bv, Bo, scores);

    Gemm3Args ga;
    ga.A[0] = Aq; ga.A[1] = Ak; ga.A[2] = Av;
    ga.B[0] = Bq; ga.B[1] = Bk; ga.B[2] = Bv;
    ga.bias[0] = bq; ga.bias[1] = bk; ga.bias[2] = bv;
    ga.C[0] = nullptr; ga.C[1] = nullptr; ga.C[2] = Pv;
    ga.C16[0] = Pq16; ga.C16[1] = Pk16; ga.C16[2] = nullptr;
    gemm3<<<dim3(64, 8, 3), 256, 0, stream>>>(ga);

    scores_kernel<<<dim3(16, 32), 256, 0, stream>>>(Pq16, Pk16, scores);
    softmax_kernel<<<1, 256, 0, stream>>>(scores, beta, attn, Mm);
    mix_kernel<<<1024, 256, 0, stream>>>(Pv, Mm, xmix);
    gemm_f16<<<dim3(64, 8), 256, 0, stream>>>(xmix, Bo, bo, out);
}